// Round 1
// baseline (402.632 us; speedup 1.0000x reference)
//
#include <hip/hip_runtime.h>
#include <stdint.h>

#define P 2048
#define R 65536
#define DD 512
#define BT 128
#define BK 32

typedef __attribute__((ext_vector_type(8))) short short8;
typedef __attribute__((ext_vector_type(4))) float f32x4;

__device__ inline unsigned short f2bf(float f) {
  unsigned int u = __float_as_uint(f);
  u += 0x7fffu + ((u >> 16) & 1u);   // round-to-nearest-even
  return (unsigned short)(u >> 16);
}

__device__ inline void gload_lds16(const void* g, void* l) {
  __builtin_amdgcn_global_load_lds(
      (const __attribute__((address_space(1))) unsigned int*)g,
      (__attribute__((address_space(3))) unsigned int*)l,
      16, 0, 0);
}

// ---- kernel 1: fp32 -> bf16 conversion + fp32 row norms; one wave per row ----
__global__ __launch_bounds__(256) void k_convert(
    const float* __restrict__ pred, const float* __restrict__ cand,
    unsigned short* __restrict__ Abf, unsigned short* __restrict__ Bbf,
    float* __restrict__ nx, float* __restrict__ ny,
    unsigned int* __restrict__ minp)
{
  if (blockIdx.x == 0 && threadIdx.x == 0) *minp = 0x7f800000u; // +inf bits
  int gw   = (blockIdx.x * 256 + threadIdx.x) >> 6;  // global wave = row
  int lane = threadIdx.x & 63;
  if (gw >= P + R) return;
  const float* src; unsigned short* dst; float* np;
  if (gw < P) { src = pred + (size_t)gw * DD; dst = Abf + (size_t)gw * DD; np = nx + gw; }
  else { int r = gw - P; src = cand + (size_t)r * DD; dst = Bbf + (size_t)r * DD; np = ny + r; }
  const float4* s4 = ((const float4*)src) + lane * 2;
  float4 v0 = s4[0], v1 = s4[1];
  float ss = v0.x*v0.x + v0.y*v0.y + v0.z*v0.z + v0.w*v0.w
           + v1.x*v1.x + v1.y*v1.y + v1.z*v1.z + v1.w*v1.w;
  union { unsigned short h[8]; uint4 v; } pk;
  pk.h[0]=f2bf(v0.x); pk.h[1]=f2bf(v0.y); pk.h[2]=f2bf(v0.z); pk.h[3]=f2bf(v0.w);
  pk.h[4]=f2bf(v1.x); pk.h[5]=f2bf(v1.y); pk.h[6]=f2bf(v1.z); pk.h[7]=f2bf(v1.w);
  *(uint4*)(dst + (size_t)lane * 8) = pk.v;
  #pragma unroll
  for (int off = 32; off; off >>= 1) ss += __shfl_down(ss, off, 64);
  if (lane == 0) *np = ss;
}

// ---- kernel 2: 128x128 bf16 MFMA tile GEMM (A·B^T) with fused min epilogue ----
__global__ __launch_bounds__(256) void k_gemm_min(
    const unsigned short* __restrict__ Abf, const unsigned short* __restrict__ Bbf,
    const float* __restrict__ nx, const float* __restrict__ ny,
    unsigned int* __restrict__ minp)
{
  __shared__ __align__(16) unsigned short As[BT * BK];   // [row][32] bf16, 8KB
  __shared__ __align__(16) unsigned short Bs[BT * BK];
  __shared__ float wmin[4];

  const int tid  = threadIdx.x;
  const int wave = tid >> 6;
  const int lane = tid & 63;
  const int by = blockIdx.x & 15;     // pred tile (fast dim -> cand tile shared by 16 adjacent blocks)
  const int bx = blockIdx.x >> 4;     // cand tile
  const int rowA0 = by * BT, rowB0 = bx * BT;
  const int wr = wave >> 1, wc = wave & 1;   // wave quadrant in 128x128

  f32x4 zero = {0.f, 0.f, 0.f, 0.f};
  f32x4 acc[4][4];
  #pragma unroll
  for (int i = 0; i < 4; ++i)
    #pragma unroll
    for (int j = 0; j < 4; ++j) acc[i][j] = zero;

  // staging: 8KB tile = 8 x (64 lanes x 16B); wave w issues chunks t=2w,2w+1 per operand.
  const int t0 = wave * 2;
  const int r0 = t0 * 16 + (lane >> 2);     // tile row for chunk t0
  const int cs = (lane & 3) * 8;            // bf16 offset within 32-wide row chunk
  const unsigned short* gA0 = Abf + (size_t)(rowA0 + r0) * DD + cs;
  const unsigned short* gA1 = Abf + (size_t)(rowA0 + r0 + 16) * DD + cs;
  const unsigned short* gB0 = Bbf + (size_t)(rowB0 + r0) * DD + cs;
  const unsigned short* gB1 = Bbf + (size_t)(rowB0 + r0 + 16) * DD + cs;
  unsigned short* lA0 = As + t0 * 512;      // t*1024 bytes
  unsigned short* lA1 = As + t0 * 512 + 512;
  unsigned short* lB0 = Bs + t0 * 512;
  unsigned short* lB1 = Bs + t0 * 512 + 512;

  // fragment read pointers (A: m=lane&15,k=quad*8+j ; B: n=lane&15,k=quad*8+j)
  const unsigned short* ap = As + ((wr * 64) + (lane & 15)) * BK + ((lane >> 4) * 8);
  const unsigned short* bp = Bs + ((wc * 64) + (lane & 15)) * BK + ((lane >> 4) * 8);

  for (int k0 = 0; k0 < DD; k0 += BK) {
    gload_lds16(gA0 + k0, lA0);
    gload_lds16(gA1 + k0, lA1);
    gload_lds16(gB0 + k0, lB0);
    gload_lds16(gB1 + k0, lB1);
    __syncthreads();

    short8 af[4], bfr[4];
    #pragma unroll
    for (int i = 0; i < 4; ++i) af[i]  = *(const short8*)(ap + i * 16 * BK);
    #pragma unroll
    for (int j = 0; j < 4; ++j) bfr[j] = *(const short8*)(bp + j * 16 * BK);
    #pragma unroll
    for (int i = 0; i < 4; ++i)
      #pragma unroll
      for (int j = 0; j < 4; ++j)
        acc[i][j] = __builtin_amdgcn_mfma_f32_16x16x32_bf16(af[i], bfr[j], acc[i][j], 0, 0, 0);
    __syncthreads();
  }

  // epilogue: d^2 = ||x||^2 + ||y||^2 - 2*dot ; C/D layout: col=lane&15, row=quad*4+reg
  const int quad = lane >> 4, n16 = lane & 15;
  float lmin = 3.4e38f;
  #pragma unroll
  for (int i = 0; i < 4; ++i) {
    const int mbase = rowA0 + wr * 64 + i * 16 + quad * 4;
    float4 nxv = *(const float4*)(nx + mbase);
    #pragma unroll
    for (int j = 0; j < 4; ++j) {
      const int n = rowB0 + wc * 64 + j * 16 + n16;
      const float nyv = ny[n];
      f32x4 a = acc[i][j];
      lmin = fminf(lmin, nxv.x + nyv - 2.0f * a[0]);
      lmin = fminf(lmin, nxv.y + nyv - 2.0f * a[1]);
      lmin = fminf(lmin, nxv.z + nyv - 2.0f * a[2]);
      lmin = fminf(lmin, nxv.w + nyv - 2.0f * a[3]);
    }
  }
  #pragma unroll
  for (int off = 32; off; off >>= 1) lmin = fminf(lmin, __shfl_down(lmin, off, 64));
  if (lane == 0) wmin[wave] = lmin;
  __syncthreads();
  if (tid == 0) {
    float m = fminf(fminf(wmin[0], wmin[1]), fminf(wmin[2], wmin[3]));
    atomicMin(minp, __float_as_uint(fmaxf(m, 0.0f)));
  }
}

// ---- fallback (only if ws too small): exact fp32 brute force ----
__global__ __launch_bounds__(64) void k_initmin(unsigned int* minp) {
  if (threadIdx.x == 0) *minp = 0x7f800000u;
}

__global__ __launch_bounds__(256) void k_brute(
    const float* __restrict__ pred, const float* __restrict__ cand,
    unsigned int* __restrict__ minp)
{
  __shared__ float yrow[DD];
  __shared__ float wm[4];
  const int c = blockIdx.x;
  for (int i = threadIdx.x; i < DD; i += 256) yrow[i] = cand[(size_t)c * DD + i];
  __syncthreads();
  float lmin = 3.4e38f;
  for (int p = threadIdx.x; p < P; p += 256) {
    const float* xp = pred + (size_t)p * DD;
    float s = 0.f;
    for (int k = 0; k < DD; ++k) { float d = xp[k] - yrow[k]; s = fmaf(d, d, s); }
    lmin = fminf(lmin, s);
  }
  #pragma unroll
  for (int off = 32; off; off >>= 1) lmin = fminf(lmin, __shfl_down(lmin, off, 64));
  if ((threadIdx.x & 63) == 0) wm[threadIdx.x >> 6] = lmin;
  __syncthreads();
  if (threadIdx.x == 0) {
    float m = fminf(fminf(wm[0], wm[1]), fminf(wm[2], wm[3]));
    atomicMin(minp, __float_as_uint(fmaxf(m, 0.0f)));
  }
}

__global__ __launch_bounds__(64) void k_finalize(const unsigned int* minp, float* out) {
  if (threadIdx.x == 0) out[0] = sqrtf(__uint_as_float(*minp));
}

extern "C" void kernel_launch(void* const* d_in, const int* in_sizes, int n_in,
                              void* d_out, int out_size, void* d_ws, size_t ws_size,
                              hipStream_t stream) {
  const float* pred = (const float*)d_in[0];
  const float* cand = (const float*)d_in[1];
  float* out = (float*)d_out;

  // ws layout: [0] min-bits | +16 floats: nx[2048] | ny[65536] | Abf bf16[2048*512] | Bbf bf16[65536*512]
  unsigned int* minp = (unsigned int*)d_ws;
  float* wsf = (float*)d_ws;
  float* nx = wsf + 16;
  float* ny = nx + P;
  unsigned short* Abf = (unsigned short*)(ny + R);
  unsigned short* Bbf = Abf + (size_t)P * DD;
  const size_t need = (size_t)(16 + P + R) * 4 + ((size_t)P * DD + (size_t)R * DD) * 2;

  if (ws_size >= need) {
    const int rows = P + R;                 // 67584 rows, 4 waves/block
    k_convert<<<rows / 4, 256, 0, stream>>>(pred, cand, Abf, Bbf, nx, ny, minp);
    k_gemm_min<<<(P / BT) * (R / BT), 256, 0, stream>>>(Abf, Bbf, nx, ny, minp);
  } else {
    k_initmin<<<1, 64, 0, stream>>>(minp);
    k_brute<<<R, 256, 0, stream>>>(pred, cand, minp);
  }
  k_finalize<<<1, 64, 0, stream>>>(minp, out);
}

// Round 2
// 398.519 us; speedup vs baseline: 1.0103x; 1.0103x over previous
//
#include <hip/hip_runtime.h>
#include <stdint.h>

#define P 2048
#define R 65536
#define DD 512
#define BT 128
#define BK 64

typedef __attribute__((ext_vector_type(8))) short short8;
typedef __attribute__((ext_vector_type(4))) float f32x4;

__device__ inline unsigned short f2bf(float f) {
  unsigned int u = __float_as_uint(f);
  u += 0x7fffu + ((u >> 16) & 1u);   // round-to-nearest-even
  return (unsigned short)(u >> 16);
}

__device__ inline void gload_lds16(const void* g, void* l) {
  __builtin_amdgcn_global_load_lds(
      (const __attribute__((address_space(1))) unsigned int*)g,
      (__attribute__((address_space(3))) unsigned int*)l,
      16, 0, 0);
}

// ---- kernel 1: fp32 -> bf16 conversion + fp32 row norms; one wave per row ----
__global__ __launch_bounds__(256) void k_convert(
    const float* __restrict__ pred, const float* __restrict__ cand,
    unsigned short* __restrict__ Abf, unsigned short* __restrict__ Bbf,
    float* __restrict__ nx, float* __restrict__ ny,
    unsigned int* __restrict__ minp)
{
  if (blockIdx.x == 0 && threadIdx.x == 0) *minp = 0x7f800000u; // +inf bits
  int gw   = (blockIdx.x * 256 + threadIdx.x) >> 6;  // global wave = row
  int lane = threadIdx.x & 63;
  if (gw >= P + R) return;
  const float* src; unsigned short* dst; float* np;
  if (gw < P) { src = pred + (size_t)gw * DD; dst = Abf + (size_t)gw * DD; np = nx + gw; }
  else { int r = gw - P; src = cand + (size_t)r * DD; dst = Bbf + (size_t)r * DD; np = ny + r; }
  const float4* s4 = ((const float4*)src) + lane * 2;
  float4 v0 = s4[0], v1 = s4[1];
  float ss = v0.x*v0.x + v0.y*v0.y + v0.z*v0.z + v0.w*v0.w
           + v1.x*v1.x + v1.y*v1.y + v1.z*v1.z + v1.w*v1.w;
  union { unsigned short h[8]; uint4 v; } pk;
  pk.h[0]=f2bf(v0.x); pk.h[1]=f2bf(v0.y); pk.h[2]=f2bf(v0.z); pk.h[3]=f2bf(v0.w);
  pk.h[4]=f2bf(v1.x); pk.h[5]=f2bf(v1.y); pk.h[6]=f2bf(v1.z); pk.h[7]=f2bf(v1.w);
  *(uint4*)(dst + (size_t)lane * 8) = pk.v;
  #pragma unroll
  for (int off = 32; off; off >>= 1) ss += __shfl_down(ss, off, 64);
  if (lane == 0) *np = ss;
}

// ---- kernel 2: 128x128 bf16 MFMA tile GEMM (A·B^T), BK=64, XOR-swizzled LDS,
//      fused min epilogue ----
// LDS layout: row-major [128][64] bf16 per operand, but the 8 16B-chunks of each
// row are stored permuted: stored_chunk = data_chunk ^ (row & 7). The permutation
// is applied on the GLOBAL source address per lane (global_load_lds writes LDS at
// wave-uniform base + lane*16, which we cannot scatter), so data lands pre-swizzled.
__global__ __launch_bounds__(256) void k_gemm_min(
    const unsigned short* __restrict__ Abf, const unsigned short* __restrict__ Bbf,
    const float* __restrict__ nx, const float* __restrict__ ny,
    unsigned int* __restrict__ minp)
{
  __shared__ __align__(16) unsigned short As[BT * BK];   // 16 KB
  __shared__ __align__(16) unsigned short Bs[BT * BK];   // 16 KB
  __shared__ float wmin[4];

  const int tid  = threadIdx.x;
  const int wave = tid >> 6;
  const int lane = tid & 63;
  const int by = blockIdx.x & 15;     // pred tile fast -> 16 adjacent blocks share cand tile
  const int bx = blockIdx.x >> 4;     // cand tile
  const int rowA0 = by * BT, rowB0 = bx * BT;
  const int wr = wave >> 1, wc = wave & 1;   // wave quadrant in 128x128

  f32x4 zero = {0.f, 0.f, 0.f, 0.f};
  f32x4 acc[4][4];
  #pragma unroll
  for (int i = 0; i < 4; ++i)
    #pragma unroll
    for (int j = 0; j < 4; ++j) acc[i][j] = zero;

  // staging: per operand 16 KB = 16 instrs x (64 lanes x 16B); wave w issues t=0..3.
  // instr (w,t): covers tile rows (w*4+t)*8 .. +7; lane L -> local row L>>3, stored
  // chunk L&7, sourcing global data chunk (L&7)^(L>>3).
  const int rloc = lane >> 3;            // 0..7
  const int cswz = (lane & 7) ^ rloc;    // swizzled source chunk
  const unsigned short* gA[4]; const unsigned short* gB[4];
  unsigned short* lA[4]; unsigned short* lB[4];
  #pragma unroll
  for (int t = 0; t < 4; ++t) {
    const int rr = (wave * 4 + t) * 8 + rloc;     // tile row 0..127
    gA[t] = Abf + (size_t)(rowA0 + rr) * DD + cswz * 8;
    gB[t] = Bbf + (size_t)(rowB0 + rr) * DD + cswz * 8;
    lA[t] = As + (wave * 4 + t) * 512;            // 1 KB per instr
    lB[t] = Bs + (wave * 4 + t) * 512;
  }

  // fragment read pointers. A frag: m=lane&15, k=quad*8+j (+32 for k-half 1).
  // Row rho = wr*64 + i*16 + m -> rho&7 == m&7; data chunk (quad+4h) stored at
  // chunk (quad+4h)^(m&7).
  const int m = lane & 15, quad = lane >> 4, mb = m & 7;
  const unsigned short* apB = As + (wr * 64 + m) * BK;
  const unsigned short* bpB = Bs + (wc * 64 + m) * BK;
  const int sw0 = ((quad    ) ^ mb) * 8;
  const int sw1 = ((quad + 4) ^ mb) * 8;

  for (int k0 = 0; k0 < DD; k0 += BK) {
    #pragma unroll
    for (int t = 0; t < 4; ++t) {
      gload_lds16(gA[t] + k0, lA[t]);
      gload_lds16(gB[t] + k0, lB[t]);
    }
    __syncthreads();

    short8 af[4], bfr[4];
    // k-half 0
    #pragma unroll
    for (int i = 0; i < 4; ++i) af[i]  = *(const short8*)(apB + i * 16 * BK + sw0);
    #pragma unroll
    for (int j = 0; j < 4; ++j) bfr[j] = *(const short8*)(bpB + j * 16 * BK + sw0);
    #pragma unroll
    for (int i = 0; i < 4; ++i)
      #pragma unroll
      for (int j = 0; j < 4; ++j)
        acc[i][j] = __builtin_amdgcn_mfma_f32_16x16x32_bf16(af[i], bfr[j], acc[i][j], 0, 0, 0);
    // k-half 1
    #pragma unroll
    for (int i = 0; i < 4; ++i) af[i]  = *(const short8*)(apB + i * 16 * BK + sw1);
    #pragma unroll
    for (int j = 0; j < 4; ++j) bfr[j] = *(const short8*)(bpB + j * 16 * BK + sw1);
    #pragma unroll
    for (int i = 0; i < 4; ++i)
      #pragma unroll
      for (int j = 0; j < 4; ++j)
        acc[i][j] = __builtin_amdgcn_mfma_f32_16x16x32_bf16(af[i], bfr[j], acc[i][j], 0, 0, 0);
    __syncthreads();
  }

  // epilogue: d^2 = ||x||^2 + ||y||^2 - 2*dot ; C/D layout: col=lane&15, row=quad*4+reg
  const int n16 = lane & 15;
  float lmin = 3.4e38f;
  #pragma unroll
  for (int i = 0; i < 4; ++i) {
    const int mbase = rowA0 + wr * 64 + i * 16 + quad * 4;
    float4 nxv = *(const float4*)(nx + mbase);
    #pragma unroll
    for (int j = 0; j < 4; ++j) {
      const int n = rowB0 + wc * 64 + j * 16 + n16;
      const float nyv = ny[n];
      f32x4 a = acc[i][j];
      lmin = fminf(lmin, nxv.x + nyv - 2.0f * a[0]);
      lmin = fminf(lmin, nxv.y + nyv - 2.0f * a[1]);
      lmin = fminf(lmin, nxv.z + nyv - 2.0f * a[2]);
      lmin = fminf(lmin, nxv.w + nyv - 2.0f * a[3]);
    }
  }
  #pragma unroll
  for (int off = 32; off; off >>= 1) lmin = fminf(lmin, __shfl_down(lmin, off, 64));
  if (lane == 0) wmin[wave] = lmin;
  __syncthreads();
  if (tid == 0) {
    float mn = fminf(fminf(wmin[0], wmin[1]), fminf(wmin[2], wmin[3]));
    atomicMin(minp, __float_as_uint(fmaxf(mn, 0.0f)));
  }
}

// ---- fallback (only if ws too small): exact fp32 brute force ----
__global__ __launch_bounds__(64) void k_initmin(unsigned int* minp) {
  if (threadIdx.x == 0) *minp = 0x7f800000u;
}

__global__ __launch_bounds__(256) void k_brute(
    const float* __restrict__ pred, const float* __restrict__ cand,
    unsigned int* __restrict__ minp)
{
  __shared__ float yrow[DD];
  __shared__ float wm[4];
  const int c = blockIdx.x;
  for (int i = threadIdx.x; i < DD; i += 256) yrow[i] = cand[(size_t)c * DD + i];
  __syncthreads();
  float lmin = 3.4e38f;
  for (int p = threadIdx.x; p < P; p += 256) {
    const float* xp = pred + (size_t)p * DD;
    float s = 0.f;
    for (int k = 0; k < DD; ++k) { float d = xp[k] - yrow[k]; s = fmaf(d, d, s); }
    lmin = fminf(lmin, s);
  }
  #pragma unroll
  for (int off = 32; off; off >>= 1) lmin = fminf(lmin, __shfl_down(lmin, off, 64));
  if ((threadIdx.x & 63) == 0) wm[threadIdx.x >> 6] = lmin;
  __syncthreads();
  if (threadIdx.x == 0) {
    float mn = fminf(fminf(wm[0], wm[1]), fminf(wm[2], wm[3]));
    atomicMin(minp, __float_as_uint(fmaxf(mn, 0.0f)));
  }
}

__global__ __launch_bounds__(64) void k_finalize(const unsigned int* minp, float* out) {
  if (threadIdx.x == 0) out[0] = sqrtf(__uint_as_float(*minp));
}

extern "C" void kernel_launch(void* const* d_in, const int* in_sizes, int n_in,
                              void* d_out, int out_size, void* d_ws, size_t ws_size,
                              hipStream_t stream) {
  const float* pred = (const float*)d_in[0];
  const float* cand = (const float*)d_in[1];
  float* out = (float*)d_out;

  // ws layout: [0] min-bits | +16 floats: nx[2048] | ny[65536] | Abf bf16[2048*512] | Bbf bf16[65536*512]
  unsigned int* minp = (unsigned int*)d_ws;
  float* wsf = (float*)d_ws;
  float* nx = wsf + 16;
  float* ny = nx + P;
  unsigned short* Abf = (unsigned short*)(ny + R);
  unsigned short* Bbf = Abf + (size_t)P * DD;
  const size_t need = (size_t)(16 + P + R) * 4 + ((size_t)P * DD + (size_t)R * DD) * 2;

  if (ws_size >= need) {
    const int rows = P + R;                 // 67584 rows, 4 waves/block
    k_convert<<<rows / 4, 256, 0, stream>>>(pred, cand, Abf, Bbf, nx, ny, minp);
    k_gemm_min<<<(P / BT) * (R / BT), 256, 0, stream>>>(Abf, Bbf, nx, ny, minp);
  } else {
    k_initmin<<<1, 64, 0, stream>>>(minp);
    k_brute<<<R, 256, 0, stream>>>(pred, cand, minp);
  }
  k_finalize<<<1, 64, 0, stream>>>(minp, out);
}